// Round 4
// baseline (7746.072 us; speedup 1.0000x reference)
//
#include <hip/hip_runtime.h>

// Problem constants
#define NP   16384      // N pair rows (B*L)
#define BSEG 2048       // segments
#define LSEG 8          // pairs per segment
#define CTX  2048
#define HID  2048
#define EMB  1024
#define MCB  4096       // codebook entries

#define BM 128
#define BN 128
#define BK 16
#define PAD 4

// ---------------------------------------------------------------------------
// fp32 tiled GEMM, single ascending-k FMA chain per output element.
//  SPLIT: A is concat(A, A2) along K, halves with row stride K1
//  BT:    B is [N,K] row-major (B^T access, VQ vs codebook)
//  EPI:   0 = +bias; 1 = +bias then leaky(0.2); 2 = np d2: (xx[r]-2*acc)+ee[c]
// ---------------------------------------------------------------------------
template<bool SPLIT, bool BT, int EPI>
__global__ __launch_bounds__(256) void gemm_f32(
    const float* __restrict__ A, const float* __restrict__ A2, int K1,
    const float* __restrict__ B, const float* __restrict__ bias,
    const float* __restrict__ xx, const float* __restrict__ ee,
    float* __restrict__ C, int M, int N, int K)
{
    __shared__ float As[BK][BM + PAD];
    __shared__ float Bs[BK][BN + PAD];

    const int tid = threadIdx.x;
    const int bm = blockIdx.y * BM;
    const int bn = blockIdx.x * BN;
    const int tx = tid & 15;        // 16 col groups of 8
    const int ty = tid >> 4;        // 16 row groups of 8

    const int ar = tid >> 2;        // 0..63 (A tile row)
    const int ak = (tid & 3) << 2;  // 0,4,8,12 (A tile k)
    const int bkr = tid >> 5;       // 0..7  (B tile k row, BT=false)
    const int bnc = (tid & 31) << 2;// 0..124 (B tile col, BT=false)

    float acc[8][8];
#pragma unroll
    for (int i = 0; i < 8; ++i)
#pragma unroll
        for (int j = 0; j < 8; ++j) acc[i][j] = 0.f;

    for (int k0 = 0; k0 < K; k0 += BK) {
        // ---- stage A tile (transposed into LDS) ----
#pragma unroll
        for (int h = 0; h < 2; ++h) {
            const int row = ar + h * 64;
            const int kg = k0 + ak;
            const float* ab;
            int kc, lda;
            if (SPLIT) {
                if (kg >= K1) { ab = A2; kc = kg - K1; } else { ab = A; kc = kg; }
                lda = K1;
            } else {
                ab = A; kc = kg; lda = K;
            }
            const float4 a4 = *(const float4*)(ab + (size_t)(bm + row) * lda + kc);
            As[ak + 0][row] = a4.x;
            As[ak + 1][row] = a4.y;
            As[ak + 2][row] = a4.z;
            As[ak + 3][row] = a4.w;
        }
        // ---- stage B tile ----
        if (!BT) {
#pragma unroll
            for (int h = 0; h < 2; ++h) {
                const int kr = bkr + h * 8;
                const float4 b4 = *(const float4*)(B + (size_t)(k0 + kr) * N + bn + bnc);
                *(float4*)(&Bs[kr][bnc]) = b4;
            }
        } else {
#pragma unroll
            for (int h = 0; h < 2; ++h) {
                const int row = ar + h * 64;   // n index
                const float4 b4 = *(const float4*)(B + (size_t)(bn + row) * K + k0 + ak);
                Bs[ak + 0][row] = b4.x;
                Bs[ak + 1][row] = b4.y;
                Bs[ak + 2][row] = b4.z;
                Bs[ak + 3][row] = b4.w;
            }
        }
        __syncthreads();

        // ---- inner product: strictly ascending k ----
#pragma unroll
        for (int kk = 0; kk < BK; ++kk) {
            float a[8], b[8];
            *(float4*)(a)     = *(const float4*)(&As[kk][ty * 8]);
            *(float4*)(a + 4) = *(const float4*)(&As[kk][ty * 8 + 4]);
            *(float4*)(b)     = *(const float4*)(&Bs[kk][tx * 8]);
            *(float4*)(b + 4) = *(const float4*)(&Bs[kk][tx * 8 + 4]);
#pragma unroll
            for (int i = 0; i < 8; ++i)
#pragma unroll
                for (int j = 0; j < 8; ++j)
                    acc[i][j] = fmaf(a[i], b[j], acc[i][j]);
        }
        __syncthreads();
    }

    // ---- epilogue ----
#pragma unroll
    for (int i = 0; i < 8; ++i) {
        const size_t r = bm + ty * 8 + i;
        float o[8];
#pragma unroll
        for (int j = 0; j < 8; ++j) {
            const int c = bn + tx * 8 + j;
            float v = acc[i][j];
            if (EPI == 2) {
                o[j] = __fadd_rn(__fsub_rn(xx[r], __fmul_rn(2.0f, v)), ee[c]);
            } else {
                v = __fadd_rn(v, bias[c]);
                if (EPI == 1) v = (v > 0.f) ? v : __fmul_rn(0.2f, v);
                o[j] = v;
            }
        }
        *(float4*)(&C[r * N + bn + tx * 8])     = *(float4*)(o);
        *(float4*)(&C[r * N + bn + tx * 8 + 4]) = *(float4*)(o + 4);
    }
}

// ---------------------------------------------------------------------------
// numpy pairwise sum-of-squares over a 1024-float row (exact np order).
// ---------------------------------------------------------------------------
__global__ __launch_bounds__(256) void np_rownorm_1024(
    const float* __restrict__ X, float* __restrict__ out, int rows)
{
    const int r = blockIdx.x * blockDim.x + threadIdx.x;
    if (r >= rows) return;
    const float* p = X + (size_t)r * EMB;
    float blk[8];
#pragma unroll
    for (int b = 0; b < 8; ++b) {
        const float* q = p + b * 128;
        float rg[8];
#pragma unroll
        for (int j = 0; j < 8; ++j) rg[j] = __fmul_rn(q[j], q[j]);
        for (int i = 8; i < 128; i += 8) {
#pragma unroll
            for (int j = 0; j < 8; ++j)
                rg[j] = __fadd_rn(rg[j], __fmul_rn(q[i + j], q[i + j]));
        }
        blk[b] = __fadd_rn(__fadd_rn(__fadd_rn(rg[0], rg[1]), __fadd_rn(rg[2], rg[3])),
                           __fadd_rn(__fadd_rn(rg[4], rg[5]), __fadd_rn(rg[6], rg[7])));
    }
    out[r] = __fadd_rn(__fadd_rn(__fadd_rn(blk[0], blk[1]), __fadd_rn(blk[2], blk[3])),
                       __fadd_rn(__fadd_rn(blk[4], blk[5]), __fadd_rn(blk[6], blk[7])));
}

// ---------------------------------------------------------------------------
// Per-segment attention weights + fold: pebar[seg] = sum_m w[m] * pe[seg*8+m]
// where w[m] = (1/8) sum_l softmax_row_l(QK^T/32)[m].  (pooled = pebar@Wv+bv
// since sum_m w[m] = 1; linearity of Wv.)  One block per segment.
// ---------------------------------------------------------------------------
__global__ __launch_bounds__(256) void attn_fold(
    const float* __restrict__ q, const float* __restrict__ k,
    const float* __restrict__ pe, float* __restrict__ pebar)
{
    const int s = blockIdx.x;
    const int tid = threadIdx.x;
    const int lane = tid & 63;
    const int wv = tid >> 6;

    __shared__ float sc[LSEG][LSEG];
    __shared__ float w[LSEG];

    const float* qb = q + (size_t)s * LSEG * EMB;
    const float* kb = k + (size_t)s * LSEG * EMB;
    const float* pb = pe + (size_t)s * LSEG * EMB;

    for (int p = wv * 16; p < wv * 16 + 16; ++p) {
        const int l = p >> 3, m = p & 7;
        float sum = 0.f;
#pragma unroll
        for (int e = 0; e < EMB; e += 64)
            sum += qb[l * EMB + e + lane] * kb[m * EMB + e + lane];
#pragma unroll
        for (int off = 32; off; off >>= 1) sum += __shfl_xor(sum, off);
        if (lane == 0) sc[l][m] = sum * (1.0f / 32.0f);
    }
    __syncthreads();

    if (tid < LSEG) {   // softmax per row
        const int l = tid;
        float mx = sc[l][0];
#pragma unroll
        for (int m = 1; m < LSEG; ++m) mx = fmaxf(mx, sc[l][m]);
        float ssum = 0.f; float ex[LSEG];
#pragma unroll
        for (int m = 0; m < LSEG; ++m) { ex[m] = expf(sc[l][m] - mx); ssum += ex[m]; }
#pragma unroll
        for (int m = 0; m < LSEG; ++m) sc[l][m] = ex[m] / ssum;
    }
    __syncthreads();
    if (tid < LSEG) {   // column mean over l
        const int m = tid;
        float t = 0.f;
#pragma unroll
        for (int l = 0; l < LSEG; ++l) t += sc[l][m];
        w[m] = t * 0.125f;
    }
    __syncthreads();

    float wr[LSEG];
#pragma unroll
    for (int m = 0; m < LSEG; ++m) wr[m] = w[m];

    const int e0 = tid * 4;   // 256 threads * 4 = 1024
    float4 o = make_float4(0.f, 0.f, 0.f, 0.f);
#pragma unroll
    for (int m = 0; m < LSEG; ++m) {
        const float4 vv = *(const float4*)(pb + m * EMB + e0);
        o.x = fmaf(wr[m], vv.x, o.x);
        o.y = fmaf(wr[m], vv.y, o.y);
        o.z = fmaf(wr[m], vv.z, o.z);
        o.w = fmaf(wr[m], vv.w, o.w);
    }
    *(float4*)(pebar + (size_t)s * EMB + e0) = o;
}

// per-row argmin over 4096 f32 d2 + gather + straight-through + sse
__global__ __launch_bounds__(256) void vq_final(
    const float* __restrict__ s, const float* __restrict__ xenc,
    const float* __restrict__ E, float* __restrict__ outq,
    float* __restrict__ outidx, double* __restrict__ sse)
{
    const int b = blockIdx.x;
    const int tid = threadIdx.x;
    __shared__ float bv[256];
    __shared__ int   bi[256];
    __shared__ double bd[256];

    float best = 3.4e38f;
    int bidx = 0x7fffffff;
    for (int m = tid; m < MCB; m += 256) {
        const float v_ = s[(size_t)b * MCB + m];
        if (v_ < best) { best = v_; bidx = m; }
    }
    bv[tid] = best; bi[tid] = bidx;
    __syncthreads();
    for (int off = 128; off; off >>= 1) {
        if (tid < off) {
            const float v2 = bv[tid + off]; const int i2 = bi[tid + off];
            if (v2 < bv[tid] || (v2 == bv[tid] && i2 < bi[tid])) { bv[tid] = v2; bi[tid] = i2; }
        }
        __syncthreads();
    }
    const int qi = bi[0];
    if (tid == 0) outidx[b] = (float)qi;
    __syncthreads();

    double part = 0.0;
    for (int e = tid; e < EMB; e += 256) {
        const float xv = xenc[(size_t)b * EMB + e];
        const float qv = E[(size_t)qi * EMB + e];
        outq[(size_t)b * EMB + e] = __fadd_rn(xv, __fsub_rn(qv, xv));
        const double d = (double)xv - (double)qv;
        part = fma(d, d, part);
    }
    bd[tid] = part;
    __syncthreads();
    for (int off = 128; off; off >>= 1) {
        if (tid < off) bd[tid] += bd[tid + off];
        __syncthreads();
    }
    if (tid == 0) atomicAdd(sse, bd[0]);
}

__global__ void finalize(const double* __restrict__ sse, float* __restrict__ outloss)
{
    const double mse = sse[0] * (1.0 / ((double)BSEG * (double)EMB));
    outloss[0] = (float)(0.25 * mse * 0.1);  // commitment_loss
    outloss[1] = (float)(mse * 0.1);         // codebook_loss
}

// ---------------------------------------------------------------------------
extern "C" void kernel_launch(void* const* d_in, const int* in_sizes, int n_in,
                              void* d_out, int out_size, void* d_ws, size_t ws_size,
                              hipStream_t stream)
{
    (void)in_sizes; (void)n_in; (void)out_size;

    const float* cc = (const float*)d_in[0];
    const float* cr = (const float*)d_in[1];
    const float* W1 = (const float*)d_in[3];
    const float* b1 = (const float*)d_in[4];
    const float* W2 = (const float*)d_in[5];
    const float* b2 = (const float*)d_in[6];
    const float* W3 = (const float*)d_in[7];
    const float* b3 = (const float*)d_in[8];
    const float* Wq = (const float*)d_in[9];
    const float* bq = (const float*)d_in[10];
    const float* Wk = (const float*)d_in[11];
    const float* bk = (const float*)d_in[12];
    const float* Wv = (const float*)d_in[13];
    const float* bv = (const float*)d_in[14];
    const float* Wm = (const float*)d_in[15];
    const float* bm = (const float*)d_in[16];
    const float* E  = (const float*)d_in[17];

    // --------- workspace-size-adaptive chunking (row-local pipeline) -------
    // Peak floats = CH*4096 (r0+r1) + 2M (xenc) + 8K (misc); s reuses r0/r1.
    const size_t W = ws_size / 4;   // floats available
    int NCH;
    if      (W >= 36u * 1024u * 1024u) NCH = 2;   // needs ~35.7M floats (143MB)
    else if (W >= 19u * 1024u * 1024u) NCH = 4;   // ~18.9M (76MB)
    else                               NCH = 8;   // ~10.5M (42MB)
    const size_t CH = NP / NCH;        // rows per chunk
    const size_t SC = CH / LSEG;       // segments per chunk

    float* ws = (float*)d_ws;
    float* r0 = ws;                         // [CH*2048): h1_c, then pe_c+q_c
    float* r1 = ws + CH * 2048;             // [CH*2048): h2_c, then k_c+pebar+pooled
    float* xenc = ws + CH * 4096;           // [2048*1024]
    float* en   = xenc + (size_t)BSEG * EMB;   // [4096]
    float* xx   = en + MCB;                    // [2048]
    double* sse = (double*)(xx + BSEG);        // 8B-aligned (even float offset)
    float* s    = ws;                       // [2048*4096] after chunk loop (r0/r1 dead)

    float* out_q    = (float*)d_out;                  // [2048*1024]
    float* out_loss = out_q + (size_t)BSEG * EMB;     // [2]
    float* out_idx  = out_loss + 2;                   // [2048]

    const dim3 blk(256);

    // codebook norms (region untouched by chunk loop)
    np_rownorm_1024<<<dim3((MCB + 255) / 256), blk, 0, stream>>>(E, en, MCB);

    for (int c = 0; c < NCH; ++c) {
        const size_t row0 = (size_t)c * CH;
        const float* ccc = cc + row0 * CTX;
        const float* crc = cr + row0 * CTX;
        float* h1c   = r0;                   // [CH,2048]
        float* h2c   = r1;                   // [CH,2048]
        float* pec   = r0;                   // [CH,1024] overwrites h1_c (dead)
        float* qc    = r0 + CH * 1024;       // [CH,1024]
        float* kc    = r1;                   // [CH,1024] overwrites h2_c (dead)
        float* pebar = r1 + CH * 1024;       // [SC,1024]
        float* pooled= pebar + SC * EMB;     // [SC,1024]
        float* xencc = xenc + (row0 / LSEG) * EMB;

        // MLP1: h1 = leaky(concat(cc,cr)@W1+b1)  [CH,2048] K=4096
        gemm_f32<true, false, 1><<<dim3(HID / BN, CH / BM), blk, 0, stream>>>(
            ccc, crc, CTX, W1, b1, nullptr, nullptr, h1c, CH, HID, 2 * CTX);
        // MLP2: h2 = leaky(h1@W2+b2)             [CH,2048] K=2048
        gemm_f32<false, false, 1><<<dim3(HID / BN, CH / BM), blk, 0, stream>>>(
            h1c, nullptr, 0, W2, b2, nullptr, nullptr, h2c, CH, HID, HID);
        // MLP3: pe = h2@W3+b3                    [CH,1024] K=2048  (reads r1, writes r0)
        gemm_f32<false, false, 0><<<dim3(EMB / BN, CH / BM), blk, 0, stream>>>(
            h2c, nullptr, 0, W3, b3, nullptr, nullptr, pec, CH, EMB, HID);
        // q,k                                    [CH,1024] K=1024
        gemm_f32<false, false, 0><<<dim3(EMB / BN, CH / BM), blk, 0, stream>>>(
            pec, nullptr, 0, Wq, bq, nullptr, nullptr, qc, CH, EMB, EMB);
        gemm_f32<false, false, 0><<<dim3(EMB / BN, CH / BM), blk, 0, stream>>>(
            pec, nullptr, 0, Wk, bk, nullptr, nullptr, kc, CH, EMB, EMB);
        // attention weights + fold onto pe rows -> pebar [SC,1024]
        attn_fold<<<dim3(SC), blk, 0, stream>>>(qc, kc, pec, pebar);
        // pooled = pebar@Wv + bv                 [SC,1024] K=1024
        gemm_f32<false, false, 0><<<dim3(EMB / BN, SC / BM), blk, 0, stream>>>(
            pebar, nullptr, 0, Wv, bv, nullptr, nullptr, pooled, SC, EMB, EMB);
        // xenc_chunk = pooled@Wm + bm            [SC,1024] K=1024
        gemm_f32<false, false, 0><<<dim3(EMB / BN, SC / BM), blk, 0, stream>>>(
            pooled, nullptr, 0, Wm, bm, nullptr, nullptr, xencc, SC, EMB, EMB);
    }

    // xx = np.sum(xenc*xenc, axis=1) (np pairwise order)
    np_rownorm_1024<<<dim3((BSEG + 255) / 256), blk, 0, stream>>>(xenc, xx, BSEG);
    // d2: s = (xx[r] - 2*xenc@E.T) + en[c]       [2048,4096] K=1024
    gemm_f32<false, true, 2><<<dim3(MCB / BN, BSEG / BM), blk, 0, stream>>>(
        xenc, nullptr, 0, E, nullptr, xx, en, s, BSEG, MCB, EMB);
    // argmin + gather + straight-through + losses
    hipMemsetAsync(sse, 0, sizeof(double), stream);
    vq_final<<<dim3(BSEG), blk, 0, stream>>>(s, xenc, E, out_q, out_idx, sse);
    finalize<<<dim3(1), dim3(1), 0, stream>>>(sse, out_loss);
}

// Round 8
// 4075.036 us; speedup vs baseline: 1.9009x; 1.9009x over previous
//
#include <hip/hip_runtime.h>

// Problem constants
#define NP   16384
#define BSEG 2048
#define LSEG 8
#define CTX  2048
#define HID  2048
#define EMB  1024
#define MCB  4096

#define NCH  8
#define CH   (NP / NCH)     // 2048 rows per chunk
#define SC   (CH / LSEG)    // 256 segments per chunk

#define LDK  40             // padded LDS inner dim (32 + 8): 80B row stride,
                            // 16B-aligned, rotates banks by 20 -> ~2-way max

typedef _Float16 f16x8 __attribute__((ext_vector_type(8)));
typedef float    f32x4 __attribute__((ext_vector_type(4)));

#define SPLIT_SCALE 4096.0f
#define INV_SPLIT   (1.0f / 4096.0f)

// ---------------------------------------------------------------------------
// MFMA split-f16 GEMM: C[M,N] = A[M,K] @ B(K,N) with B stored transposed+split
// as Ba,Bb [N,K] f16.  A either split pair Aa,Ab [M,K] (ASRC=0) or two f32
// halves concat along K (ASRC=1: Af0,Af1 each [M,K1], K=2*K1).
// value = acc0 + acc1/4096 where acc1 collects x1*y2s + x2s*y1.
// EPI: 0 = bias+leaky -> pair out
//      1 = bias       -> pair out + f32 out
//      2 = bias       -> f32 out only
//      3 = bias       -> pair out only
//      4 = d2: (xx[r] - 2*g) + en[c] -> f32 out
// Tile: 128(M) x 64(N), BK=32, 4 waves (2x2), wave-tile 64x32 (4x2 frags).
// ---------------------------------------------------------------------------
template<int ASRC, int EPI>
__global__ __launch_bounds__(256) void gemm16(
    const _Float16* __restrict__ Aa, const _Float16* __restrict__ Ab,
    const float* __restrict__ Af0, const float* __restrict__ Af1, int K1,
    const _Float16* __restrict__ Ba, const _Float16* __restrict__ Bb,
    const float* __restrict__ bias, const float* __restrict__ xx,
    const float* __restrict__ en,
    _Float16* __restrict__ Ca, _Float16* __restrict__ Cb, float* __restrict__ Cf,
    int M, int N, int K)
{
    __shared__ _Float16 LA1[128][LDK];
    __shared__ _Float16 LA2[128][LDK];
    __shared__ _Float16 LB1[64][LDK];
    __shared__ _Float16 LB2[64][LDK];

    const int tid  = threadIdx.x;
    const int bm   = blockIdx.y * 128;
    const int bn   = blockIdx.x * 64;
    const int wid  = tid >> 6, lane = tid & 63;
    const int wm   = wid >> 1, wn = wid & 1;
    const int lr   = lane & 15, lg = lane >> 4;

    f32x4 acc0[4][2], acc1[4][2];
#pragma unroll
    for (int i = 0; i < 4; ++i)
#pragma unroll
        for (int j = 0; j < 2; ++j) {
            acc0[i][j] = (f32x4)0.0f;
            acc1[i][j] = (f32x4)0.0f;
        }

    for (int k0 = 0; k0 < K; k0 += 32) {
        __syncthreads();
        // ---- stage A tile: ids 0..511 -> (row=id>>2, kchunk=(id&3)*8) ----
#pragma unroll
        for (int j = 0; j < 2; ++j) {
            const int id  = tid + j * 256;
            const int row = id >> 2;
            const int kc  = (id & 3) * 8;
            const int kg  = k0 + kc;
            if constexpr (ASRC == 0) {
                const size_t o = (size_t)(bm + row) * K + kg;
                *(f16x8*)(&LA1[row][kc]) = *(const f16x8*)(Aa + o);
                *(f16x8*)(&LA2[row][kc]) = *(const f16x8*)(Ab + o);
            } else {
                const float* src = (kg < K1)
                    ? (Af0 + (size_t)(bm + row) * K1 + kg)
                    : (Af1 + (size_t)(bm + row) * K1 + (kg - K1));
                const float4 u0 = *(const float4*)(src);
                const float4 u1 = *(const float4*)(src + 4);
                const float uu[8] = {u0.x, u0.y, u0.z, u0.w, u1.x, u1.y, u1.z, u1.w};
                f16x8 v1, v2;
#pragma unroll
                for (int e = 0; e < 8; ++e) {
                    const _Float16 h = (_Float16)uu[e];
                    v1[e] = h;
                    v2[e] = (_Float16)((uu[e] - (float)h) * SPLIT_SCALE);
                }
                *(f16x8*)(&LA1[row][kc]) = v1;
                *(f16x8*)(&LA2[row][kc]) = v2;
            }
        }
        // ---- stage B tile: ids 0..255 -> (row=id>>2 of 64, kchunk) ----
        {
            const int row = tid >> 2;
            const int kc  = (tid & 3) * 8;
            const size_t o = (size_t)(bn + row) * K + k0 + kc;
            *(f16x8*)(&LB1[row][kc]) = *(const f16x8*)(Ba + o);
            *(f16x8*)(&LB2[row][kc]) = *(const f16x8*)(Bb + o);
        }
        __syncthreads();

        // ---- fragments + 3-pass MFMA ----
        f16x8 a1[4], a2[4], b1[2], b2[2];
#pragma unroll
        for (int mi = 0; mi < 4; ++mi) {
            a1[mi] = *(const f16x8*)(&LA1[wm * 64 + mi * 16 + lr][lg * 8]);
            a2[mi] = *(const f16x8*)(&LA2[wm * 64 + mi * 16 + lr][lg * 8]);
        }
#pragma unroll
        for (int ni = 0; ni < 2; ++ni) {
            b1[ni] = *(const f16x8*)(&LB1[wn * 32 + ni * 16 + lr][lg * 8]);
            b2[ni] = *(const f16x8*)(&LB2[wn * 32 + ni * 16 + lr][lg * 8]);
        }
#pragma unroll
        for (int mi = 0; mi < 4; ++mi)
#pragma unroll
            for (int ni = 0; ni < 2; ++ni) {
                acc0[mi][ni] = __builtin_amdgcn_mfma_f32_16x16x32_f16(a1[mi], b1[ni], acc0[mi][ni], 0, 0, 0);
                acc1[mi][ni] = __builtin_amdgcn_mfma_f32_16x16x32_f16(a1[mi], b2[ni], acc1[mi][ni], 0, 0, 0);
                acc1[mi][ni] = __builtin_amdgcn_mfma_f32_16x16x32_f16(a2[mi], b1[ni], acc1[mi][ni], 0, 0, 0);
            }
    }

    // ---- epilogue: D row=(lane>>4)*4+r, col=lane&15 within 16x16 frag ----
#pragma unroll
    for (int mi = 0; mi < 4; ++mi)
#pragma unroll
        for (int ni = 0; ni < 2; ++ni)
#pragma unroll
            for (int r = 0; r < 4; ++r) {
                const int row = bm + wm * 64 + mi * 16 + lg * 4 + r;
                const int col = bn + wn * 32 + ni * 16 + lr;
                float v = acc0[mi][ni][r] + acc1[mi][ni][r] * INV_SPLIT;
                const size_t o = (size_t)row * N + col;
                if constexpr (EPI == 4) {
                    Cf[o] = __fadd_rn(__fsub_rn(xx[row], __fmul_rn(2.0f, v)), en[col]);
                } else {
                    v += bias[col];
                    if constexpr (EPI == 0) v = (v > 0.f) ? v : 0.2f * v;
                    if constexpr (EPI == 1 || EPI == 2) Cf[o] = v;
                    if constexpr (EPI != 2) {
                        const _Float16 h = (_Float16)v;
                        Ca[o] = h;
                        Cb[o] = (_Float16)((v - (float)h) * SPLIT_SCALE);
                    }
                }
            }
}

// ---------------------------------------------------------------------------
// Weight transpose + split: W [K,N] f32 -> Wa,Wb [N,K] f16 pair.
// ---------------------------------------------------------------------------
__global__ __launch_bounds__(256) void wtrans_split(
    const float* __restrict__ W, _Float16* __restrict__ Wa,
    _Float16* __restrict__ Wb, int K, int N)
{
    __shared__ float t[32][33];
    const int tx = threadIdx.x, ty = threadIdx.y;     // (32,8)
    const int n0 = blockIdx.x * 32, k0 = blockIdx.y * 32;
#pragma unroll
    for (int j = 0; j < 4; ++j)
        t[ty + j * 8][tx] = W[(size_t)(k0 + ty + j * 8) * N + n0 + tx];
    __syncthreads();
#pragma unroll
    for (int j = 0; j < 4; ++j) {
        const int n = ty + j * 8;
        const float v = t[tx][n];
        const size_t o = (size_t)(n0 + n) * K + k0 + tx;
        const _Float16 h = (_Float16)v;
        Wa[o] = h;
        Wb[o] = (_Float16)((v - (float)h) * SPLIT_SCALE);
    }
}

// elementwise split (for E; already [N,K] layout)
__global__ __launch_bounds__(256) void split_f32(
    const float* __restrict__ X, _Float16* __restrict__ Xa,
    _Float16* __restrict__ Xb, size_t n)
{
    for (size_t i = (size_t)blockIdx.x * blockDim.x + threadIdx.x; i < n;
         i += (size_t)gridDim.x * blockDim.x) {
        const float v = X[i];
        const _Float16 h = (_Float16)v;
        Xa[i] = h;
        Xb[i] = (_Float16)((v - (float)h) * SPLIT_SCALE);
    }
}

// ---------------------------------------------------------------------------
// numpy pairwise sum-of-squares over 1024-float rows (f32, np order).
// ---------------------------------------------------------------------------
__global__ __launch_bounds__(256) void np_rownorm_1024(
    const float* __restrict__ X, float* __restrict__ out, int rows)
{
    const int r = blockIdx.x * blockDim.x + threadIdx.x;
    if (r >= rows) return;
    const float* p = X + (size_t)r * EMB;
    float blk[8];
#pragma unroll
    for (int b = 0; b < 8; ++b) {
        const float* q = p + b * 128;
        float rg[8];
#pragma unroll
        for (int j = 0; j < 8; ++j) rg[j] = __fmul_rn(q[j], q[j]);
        for (int i = 8; i < 128; i += 8) {
#pragma unroll
            for (int j = 0; j < 8; ++j)
                rg[j] = __fadd_rn(rg[j], __fmul_rn(q[i + j], q[i + j]));
        }
        blk[b] = __fadd_rn(__fadd_rn(__fadd_rn(rg[0], rg[1]), __fadd_rn(rg[2], rg[3])),
                           __fadd_rn(__fadd_rn(rg[4], rg[5]), __fadd_rn(rg[6], rg[7])));
    }
    out[r] = __fadd_rn(__fadd_rn(__fadd_rn(blk[0], blk[1]), __fadd_rn(blk[2], blk[3])),
                       __fadd_rn(__fadd_rn(blk[4], blk[5]), __fadd_rn(blk[6], blk[7])));
}

// ---------------------------------------------------------------------------
// Per-segment attention weights + fold into pebar (split-f16 output):
// pebar[seg] = sum_m w[m]*pe[seg*8+m],  w = mean_l softmax_l(QK^T/32).
// ---------------------------------------------------------------------------
__global__ __launch_bounds__(256) void attn_fold(
    const float* __restrict__ q, const float* __restrict__ k,
    const float* __restrict__ pe, _Float16* __restrict__ Pa,
    _Float16* __restrict__ Pb)
{
    const int s = blockIdx.x;
    const int tid = threadIdx.x;
    const int lane = tid & 63;
    const int wv = tid >> 6;

    __shared__ float sc[LSEG][LSEG];
    __shared__ float w[LSEG];

    const float* qb = q + (size_t)s * LSEG * EMB;
    const float* kb = k + (size_t)s * LSEG * EMB;
    const float* pb = pe + (size_t)s * LSEG * EMB;

    for (int p = wv * 16; p < wv * 16 + 16; ++p) {
        const int l = p >> 3, m = p & 7;
        float sum = 0.f;
#pragma unroll
        for (int e = 0; e < EMB; e += 64)
            sum += qb[l * EMB + e + lane] * kb[m * EMB + e + lane];
#pragma unroll
        for (int off = 32; off; off >>= 1) sum += __shfl_xor(sum, off);
        if (lane == 0) sc[l][m] = sum * (1.0f / 32.0f);
    }
    __syncthreads();

    if (tid < LSEG) {
        const int l = tid;
        float mx = sc[l][0];
#pragma unroll
        for (int m = 1; m < LSEG; ++m) mx = fmaxf(mx, sc[l][m]);
        float ssum = 0.f; float ex[LSEG];
#pragma unroll
        for (int m = 0; m < LSEG; ++m) { ex[m] = expf(sc[l][m] - mx); ssum += ex[m]; }
#pragma unroll
        for (int m = 0; m < LSEG; ++m) sc[l][m] = ex[m] / ssum;
    }
    __syncthreads();
    if (tid < LSEG) {
        const int m = tid;
        float t = 0.f;
#pragma unroll
        for (int l = 0; l < LSEG; ++l) t += sc[l][m];
        w[m] = t * 0.125f;
    }
    __syncthreads();

    float wr[LSEG];
#pragma unroll
    for (int m = 0; m < LSEG; ++m) wr[m] = w[m];

    const int e0 = tid * 4;
    float o[4] = {0.f, 0.f, 0.f, 0.f};
#pragma unroll
    for (int m = 0; m < LSEG; ++m) {
        const float4 vv = *(const float4*)(pb + m * EMB + e0);
        o[0] = fmaf(wr[m], vv.x, o[0]);
        o[1] = fmaf(wr[m], vv.y, o[1]);
        o[2] = fmaf(wr[m], vv.z, o[2]);
        o[3] = fmaf(wr[m], vv.w, o[3]);
    }
#pragma unroll
    for (int j = 0; j < 4; ++j) {
        const size_t idx = (size_t)s * EMB + e0 + j;
        const _Float16 h = (_Float16)o[j];
        Pa[idx] = h;
        Pb[idx] = (_Float16)((o[j] - (float)h) * SPLIT_SCALE);
    }
}

// per-row argmin over 4096 f32 d2 + gather + straight-through + sse
__global__ __launch_bounds__(256) void vq_final(
    const float* __restrict__ s, const float* __restrict__ xenc,
    const float* __restrict__ E, float* __restrict__ outq,
    float* __restrict__ outidx, double* __restrict__ sse)
{
    const int b = blockIdx.x;
    const int tid = threadIdx.x;
    __shared__ float bv[256];
    __shared__ int   bi[256];
    __shared__ double bd[256];

    float best = 3.4e38f;
    int bidx = 0x7fffffff;
    for (int m = tid; m < MCB; m += 256) {
        const float v_ = s[(size_t)b * MCB + m];
        if (v_ < best) { best = v_; bidx = m; }
    }
    bv[tid] = best; bi[tid] = bidx;
    __syncthreads();
    for (int off = 128; off; off >>= 1) {
        if (tid < off) {
            const float v2 = bv[tid + off]; const int i2 = bi[tid + off];
            if (v2 < bv[tid] || (v2 == bv[tid] && i2 < bi[tid])) { bv[tid] = v2; bi[tid] = i2; }
        }
        __syncthreads();
    }
    const int qi = bi[0];
    if (tid == 0) outidx[b] = (float)qi;
    __syncthreads();

    double part = 0.0;
    for (int e = tid; e < EMB; e += 256) {
        const float xv = xenc[(size_t)b * EMB + e];
        const float qv = E[(size_t)qi * EMB + e];
        outq[(size_t)b * EMB + e] = __fadd_rn(xv, __fsub_rn(qv, xv));
        const double d = (double)xv - (double)qv;
        part = fma(d, d, part);
    }
    bd[tid] = part;
    __syncthreads();
    for (int off = 128; off; off >>= 1) {
        if (tid < off) bd[tid] += bd[tid + off];
        __syncthreads();
    }
    if (tid == 0) atomicAdd(sse, bd[0]);
}

__global__ void finalize(const double* __restrict__ sse, float* __restrict__ outloss)
{
    const double mse = sse[0] * (1.0 / ((double)BSEG * (double)EMB));
    outloss[0] = (float)(0.25 * mse * 0.1);
    outloss[1] = (float)(mse * 0.1);
}

// ---------------------------------------------------------------------------
extern "C" void kernel_launch(void* const* d_in, const int* in_sizes, int n_in,
                              void* d_out, int out_size, void* d_ws, size_t ws_size,
                              hipStream_t stream)
{
    (void)in_sizes; (void)n_in; (void)out_size; (void)ws_size;

    const float* cc = (const float*)d_in[0];
    const float* cr = (const float*)d_in[1];
    const float* W1 = (const float*)d_in[3];
    const float* b1 = (const float*)d_in[4];
    const float* W2 = (const float*)d_in[5];
    const float* b2 = (const float*)d_in[6];
    const float* W3 = (const float*)d_in[7];
    const float* b3 = (const float*)d_in[8];
    const float* Wq = (const float*)d_in[9];
    const float* bq = (const float*)d_in[10];
    const float* Wk = (const float*)d_in[11];
    const float* bk = (const float*)d_in[12];
    const float* Wv = (const float*)d_in[13];
    const float* bv = (const float*)d_in[14];
    const float* Wm = (const float*)d_in[15];
    const float* bm = (const float*)d_in[16];
    const float* E  = (const float*)d_in[17];

    // ---------------- static workspace layout (bytes), total ~134 MiB ------
    // (round-4 counters prove NCH=2 ran there -> ws_size >= 151 MB)
    char* base = (char*)d_ws;
    size_t off = 0;
    auto alloc = [&](size_t bytes) { char* p = base + off; off += (bytes + 255) & ~(size_t)255; return p; };

    _Float16* W1a = (_Float16*)alloc((size_t)2048 * 4096 * 2);  // 16.78MB
    _Float16* W1b = (_Float16*)alloc((size_t)2048 * 4096 * 2);
    _Float16* W2a = (_Float16*)alloc((size_t)2048 * 2048 * 2);
    _Float16* W2b = (_Float16*)alloc((size_t)2048 * 2048 * 2);
    _Float16* W3a = (_Float16*)alloc((size_t)1024 * 2048 * 2);
    _Float16* W3b = (_Float16*)alloc((size_t)1024 * 2048 * 2);
    _Float16* Wqa = (_Float16*)alloc((size_t)1024 * 1024 * 2);
    _Float16* Wqb = (_Float16*)alloc((size_t)1024 * 1024 * 2);
    _Float16* Wka = (_Float16*)alloc((size_t)1024 * 1024 * 2);
    _Float16* Wkb = (_Float16*)alloc((size_t)1024 * 1024 * 2);
    _Float16* Wva = (_Float16*)alloc((size_t)1024 * 1024 * 2);
    _Float16* Wvb = (_Float16*)alloc((size_t)1024 * 1024 * 2);
    _Float16* Wma = (_Float16*)alloc((size_t)1024 * 1024 * 2);
    _Float16* Wmb = (_Float16*)alloc((size_t)1024 * 1024 * 2);
    _Float16* Pa  = (_Float16*)alloc((size_t)BSEG * EMB * 2);
    _Float16* Pb  = (_Float16*)alloc((size_t)BSEG * EMB * 2);
    float*    xenc = (float*)alloc((size_t)BSEG * EMB * 4);
    _Float16* xea = (_Float16*)alloc((size_t)BSEG * EMB * 2);
    _Float16* xeb = (_Float16*)alloc((size_t)BSEG * EMB * 2);
    float*    en  = (float*)alloc(MCB * 4);
    float*    xx  = (float*)alloc(BSEG * 4);
    double*   sse = (double*)alloc(4096);
    char*     S0  = alloc((size_t)CH * 8192);   // 16.78MB chunk scratch
    char*     S1  = alloc((size_t)CH * 8192);   // 16.78MB chunk scratch

    // chunk-scratch overlays
    _Float16* h1a = (_Float16*)S0;                       // [CH,2048]
    _Float16* h1b = h1a + (size_t)CH * HID;
    _Float16* h2a = (_Float16*)S1;
    _Float16* h2b = h2a + (size_t)CH * HID;
    float*    pef = (float*)S0;                          // [CH,1024] f32
    _Float16* pea = (_Float16*)(S0 + (size_t)CH * 1024 * 4);
    _Float16* peb = pea + (size_t)CH * EMB;
    float*    qf  = (float*)S1;                          // [CH,1024]
    float*    kf  = qf + (size_t)CH * EMB;
    // post-chunk overlays
    _Float16* poa = (_Float16*)S0;                       // pooled pair [2048,1024]
    _Float16* pob = poa + (size_t)BSEG * EMB;
    _Float16* E1  = (_Float16*)S1;                       // E pair [4096,1024]
    _Float16* E2  = E1 + (size_t)MCB * EMB;
    float*    s   = (float*)W1a;                         // [2048,4096] (W1 dead)

    float* out_q    = (float*)d_out;
    float* out_loss = out_q + (size_t)BSEG * EMB;
    float* out_idx  = out_loss + 2;

    const dim3 blk(256);
    const dim3 tblk(32, 8);

    // ---- weight prep (transpose + split) ----
    wtrans_split<<<dim3(HID / 32, 2 * CTX / 32), tblk, 0, stream>>>(W1, W1a, W1b, 2 * CTX, HID);
    wtrans_split<<<dim3(HID / 32, HID / 32), tblk, 0, stream>>>(W2, W2a, W2b, HID, HID);
    wtrans_split<<<dim3(EMB / 32, HID / 32), tblk, 0, stream>>>(W3, W3a, W3b, HID, EMB);
    wtrans_split<<<dim3(EMB / 32, EMB / 32), tblk, 0, stream>>>(Wq, Wqa, Wqb, EMB, EMB);
    wtrans_split<<<dim3(EMB / 32, EMB / 32), tblk, 0, stream>>>(Wk, Wka, Wkb, EMB, EMB);
    wtrans_split<<<dim3(EMB / 32, EMB / 32), tblk, 0, stream>>>(Wv, Wva, Wvb, EMB, EMB);
    wtrans_split<<<dim3(EMB / 32, EMB / 32), tblk, 0, stream>>>(Wm, Wma, Wmb, EMB, EMB);
    np_rownorm_1024<<<dim3((MCB + 255) / 256), blk, 0, stream>>>(E, en, MCB);

    // ---- chunked MLP + attention ----
    for (int c = 0; c < NCH; ++c) {
        const size_t row0 = (size_t)c * CH;
        // MLP1: h1 = leaky(concat(cc,cr)@W1)   [CH,2048] K=4096
        gemm16<1, 0><<<dim3(HID / 64, CH / 128), blk, 0, stream>>>(
            nullptr, nullptr, cc + row0 * CTX, cr + row0 * CTX, CTX,
            W1a, W1b, b1, nullptr, nullptr, h1a, h1b, nullptr, CH, HID, 2 * CTX);
        // MLP2: h2 = leaky(h1@W2)              [CH,2048] K=2048
        gemm16<0, 0><<<dim3(HID / 64, CH / 128), blk, 0, stream>>>(
            h1a, h1b, nullptr, nullptr, 0,
            W2a, W2b, b2, nullptr, nullptr, h2a, h2b, nullptr, CH, HID, HID);
        // MLP3: pe = h2@W3 (f32 + pair)        [CH,1024] K=2048
        gemm16<0, 1><<<dim3(EMB / 64, CH / 128), blk, 0, stream>>>(
            h2a, h2b, nullptr, nullptr, 0,
            W3a, W3b, b3, nullptr, nullptr, pea, peb, pef, CH, EMB, HID);
        // q,k (f32 only)                       [CH,1024] K=1024
        gemm16<0, 2><<<dim3(EMB / 64, CH / 128), blk, 0, stream>>>(
            pea, peb, nullptr, nullptr, 0,
            Wqa, Wqb, bq, nullptr, nullptr, nullptr, nullptr, qf, CH, EMB, EMB);
        gemm16<0, 2><<<dim3(EMB / 64, CH / 128), blk, 0, stream>>>(
            pea, peb, nullptr, nullptr, 0,
            Wka, Wkb, bk, nullptr, nullptr, nullptr, nullptr, kf, CH, EMB, EMB);
        // attention fold -> pebar pair slice
        attn_fold<<<dim3(SC), blk, 0, stream>>>(
            qf, kf, pef, Pa + (row0 / LSEG) * EMB, Pb + (row0 / LSEG) * EMB);
    }

    // ---- tail: Wv, E-split, Wm, d2, argmin ----
    // pooled = pebar@Wv (pair out)            [2048,1024] K=1024
    gemm16<0, 3><<<dim3(EMB / 64, BSEG / 128), blk, 0, stream>>>(
        Pa, Pb, nullptr, nullptr, 0,
        Wva, Wvb, bv, nullptr, nullptr, poa, pob, nullptr, BSEG, EMB, EMB);
    split_f32<<<dim3(2048), blk, 0, stream>>>(E, E1, E2, (size_t)MCB * EMB);
    // xenc = pooled@Wm (f32 + pair)           [2048,1024] K=1024
    gemm16<0, 1><<<dim3(EMB / 64, BSEG / 128), blk, 0, stream>>>(
        poa, pob, nullptr, nullptr, 0,
        Wma, Wmb, bm, nullptr, nullptr, xea, xeb, xenc, BSEG, EMB, EMB);
    np_rownorm_1024<<<dim3((BSEG + 255) / 256), blk, 0, stream>>>(xenc, xx, BSEG);
    // d2: s = (xx - 2*xenc@E^T) + en          [2048,4096] K=1024
    gemm16<0, 4><<<dim3(MCB / 64, BSEG / 128), blk, 0, stream>>>(
        xea, xeb, nullptr, nullptr, 0,
        E1, E2, nullptr, xx, en, nullptr, nullptr, s, BSEG, MCB, EMB);
    hipMemsetAsync(sse, 0, sizeof(double), stream);
    vq_final<<<dim3(BSEG), blk, 0, stream>>>(s, xenc, E, out_q, out_idx, sse);
    finalize<<<dim3(1), dim3(1), 0, stream>>>(sse, out_loss);
}